// Round 16
// baseline (74.059 us; speedup 1.0000x reference)
//
#include <hip/hip_runtime.h>

#define BB 4
#define NN 2048
#define FF 512
#define ALPHA 0.2f

typedef unsigned short u16;
typedef unsigned int u32;
typedef __attribute__((ext_vector_type(8))) short bf16x8;
typedef __attribute__((ext_vector_type(4))) float f32x4;

__device__ __forceinline__ u16 f2bf(float x) {
  union { float f; u32 u; } v; v.f = x;
  u32 r = v.u + 0x7fffu + ((v.u >> 16) & 1u);
  return (u16)(r >> 16);
}
__device__ __forceinline__ float leaky(float x) { return x >= 0.f ? x : ALPHA * x; }

// -------------------------------------------------------------------------
// K0: fused  (bid < 64)  wt[f][k] = bf16(W[k][f])   64x64 LDS transpose
//            (bid >= 64) wa1/wa2 = W^T @ a halves   4 rows per block
// Both only read W / a — independent, so one dispatch.
// -------------------------------------------------------------------------
__global__ __launch_bounds__(256) void k_wawt(const float* __restrict__ W,
                                              const float* __restrict__ a,
                                              float* __restrict__ wa1,
                                              float* __restrict__ wa2,
                                              u16* __restrict__ wt) {
  __shared__ float T[64][65];
  const int tid = threadIdx.x;
  if (blockIdx.x < 64) {
    const int k0 = (blockIdx.x & 7) * 64, f0 = (blockIdx.x >> 3) * 64;
    const int c = tid & 15, r0 = tid >> 4;
#pragma unroll
    for (int p = 0; p < 4; p++) {
      const int k = r0 + p * 16;
      float4 v = *(const float4*)(W + (size_t)(k0 + k) * FF + f0 + c * 4);
      T[c * 4 + 0][k] = v.x;
      T[c * 4 + 1][k] = v.y;
      T[c * 4 + 2][k] = v.z;
      T[c * 4 + 3][k] = v.w;
    }
    __syncthreads();
    const int kc = tid & 7, fr0 = tid >> 3;
#pragma unroll
    for (int p = 0; p < 2; p++) {
      const int f = fr0 + p * 32;
      union { uint4 q; u16 s[8]; } o;
#pragma unroll
      for (int q = 0; q < 8; q++) o.s[q] = f2bf(T[f][kc * 8 + q]);
      *(uint4*)(wt + (size_t)(f0 + f) * FF + k0 + kc * 8) = o.q;
    }
  } else {
    const int wave = tid >> 6, lane = tid & 63;
    const int k = (blockIdx.x - 64) * 4 + wave;
    const int f0 = lane * 8;
    float4 w0 = *(const float4*)(W + (size_t)k * FF + f0);
    float4 w1 = *(const float4*)(W + (size_t)k * FF + f0 + 4);
    float4 p0 = *(const float4*)(a + f0);
    float4 p1 = *(const float4*)(a + f0 + 4);
    float4 q0 = *(const float4*)(a + FF + f0);
    float4 q1 = *(const float4*)(a + FF + f0 + 4);
    float d1 = w0.x*p0.x + w0.y*p0.y + w0.z*p0.z + w0.w*p0.w
             + w1.x*p1.x + w1.y*p1.y + w1.z*p1.z + w1.w*p1.w;
    float d2 = w0.x*q0.x + w0.y*q0.y + w0.z*q0.z + w0.w*q0.w
             + w1.x*q1.x + w1.y*q1.y + w1.z*q1.z + w1.w*q1.w;
#pragma unroll
    for (int o = 32; o; o >>= 1) { d1 += __shfl_xor(d1, o); d2 += __shfl_xor(d2, o); }
    if (lane == 0) { wa1[k] = d1; wa2[k] = d2; }
  }
}

// -------------------------------------------------------------------------
// K0b: s1/s2 = h·wa1 / h·wa2  (fp32)  +  emit hbf = bf16(h)  (coalesced)
// -------------------------------------------------------------------------
__global__ __launch_bounds__(256) void k_s(const float* __restrict__ h,
                                           const float* __restrict__ wa1,
                                           const float* __restrict__ wa2,
                                           float* __restrict__ s1,
                                           float* __restrict__ s2,
                                           u16* __restrict__ hbf) {
  const int wave = threadIdx.x >> 6, lane = threadIdx.x & 63;
  const int row = blockIdx.x * 4 + wave;  // 0..8191
  const int f0 = lane * 8;
  float4 h0 = *(const float4*)(h + (size_t)row * FF + f0);
  float4 h1 = *(const float4*)(h + (size_t)row * FF + f0 + 4);
  float4 p0 = *(const float4*)(wa1 + f0);
  float4 p1 = *(const float4*)(wa1 + f0 + 4);
  float4 q0 = *(const float4*)(wa2 + f0);
  float4 q1 = *(const float4*)(wa2 + f0 + 4);
  union { uint4 q; u16 s[8]; } ob;
  ob.s[0] = f2bf(h0.x); ob.s[1] = f2bf(h0.y); ob.s[2] = f2bf(h0.z); ob.s[3] = f2bf(h0.w);
  ob.s[4] = f2bf(h1.x); ob.s[5] = f2bf(h1.y); ob.s[6] = f2bf(h1.z); ob.s[7] = f2bf(h1.w);
  *(uint4*)(hbf + (size_t)row * FF + f0) = ob.q;
  float d1 = h0.x*p0.x + h0.y*p0.y + h0.z*p0.z + h0.w*p0.w
           + h1.x*p1.x + h1.y*p1.y + h1.z*p1.z + h1.w*p1.w;
  float d2 = h0.x*q0.x + h0.y*q0.y + h0.z*q0.z + h0.w*q0.w
           + h1.x*q1.x + h1.y*q1.y + h1.z*q1.z + h1.w*q1.w;
#pragma unroll
  for (int o = 32; o; o >>= 1) { d1 += __shfl_xor(d1, o); d2 += __shfl_xor(d2, o); }
  if (lane == 0) { s1[row] = d1; s2[row] = d2; }
}

// -------------------------------------------------------------------------
// K2: stream adj once; emit P_u[b][i][j] bf16 (16B stores) + lpart partials.
// -------------------------------------------------------------------------
__global__ __launch_bounds__(512) void k_l(const int* __restrict__ adj,
                                           const float* __restrict__ s1,
                                           const float* __restrict__ s2,
                                           float* __restrict__ lpart,
                                           u16* __restrict__ P) {
  const int b = blockIdx.y, t = threadIdx.x;
  const int rh = t >> 8;                 // row half: 0/1
  const int tj = t & 255, j8 = tj * 8;
  const int i0 = blockIdx.x * 16 + rh * 8;
  float s2v[8];
  *(float4*)(&s2v[0]) = *(const float4*)(s2 + b * NN + j8);
  *(float4*)(&s2v[4]) = *(const float4*)(s2 + b * NN + j8 + 4);
  float accv[8];
#pragma unroll
  for (int k = 0; k < 8; k++) accv[k] = 0.f;
  const int* abase = adj + ((size_t)b * NN + i0) * NN + j8;
  u16* pbase = P + ((size_t)b * NN + i0) * NN + j8;
#pragma unroll 4
  for (int i = 0; i < 8; i++) {
    int4 A0 = *(const int4*)(abase + (size_t)i * NN);
    int4 A1 = *(const int4*)(abase + (size_t)i * NN + 4);
    const float s1i = s1[b * NN + i0 + i];
    int av[8] = {A0.x, A0.y, A0.z, A0.w, A1.x, A1.y, A1.z, A1.w};
    union { uint4 q; u16 s[8]; } o;
#pragma unroll
    for (int k = 0; k < 8; k++) {
      float p = (av[k] > 0) ? __expf(leaky(s1i + s2v[k])) : 0.f;
      accv[k] += p;
      o.s[k] = f2bf(p);
    }
    *(uint4*)(pbase + (size_t)i * NN) = o.q;
  }
  float* lp = lpart + (size_t)(blockIdx.x * 2 + rh) * (BB * NN) + b * NN + j8;
  *(float4*)lp = *(float4*)(&accv[0]);
  *(float4*)(lp + 4) = *(float4*)(&accv[4]);
}

// -------------------------------------------------------------------------
// K2b: l[idx] = sum over 256 chunks of lpart[c][idx].
// grid 256 blocks; block owns 32 idx; 8-way chunk split + LDS reduce.
// -------------------------------------------------------------------------
__global__ __launch_bounds__(256) void k_lred(const float* __restrict__ lpart,
                                              float* __restrict__ l) {
  __shared__ float red[8][32];
  const int t = threadIdx.x;
  const int io = t & 31, cg = t >> 5;        // idx-offset, chunk-group
  const int idx = blockIdx.x * 32 + io;
  float s = 0.f;
#pragma unroll 8
  for (int c = cg; c < 256; c += 8) s += lpart[(size_t)c * (BB * NN) + idx];
  red[cg][io] = s;
  __syncthreads();
  if (t < 32) {
    float r = 0.f;
#pragma unroll
    for (int g = 0; g < 8; g++) r += red[g][t];
    l[blockIdx.x * 32 + t] = r;
  }
}

// -------------------------------------------------------------------------
// K3: whT[b][f][i] = bf16( (h@W)[i][f] * 1/l[b][i] ) — pipelined GEMM.
// (unchanged from round 14)
// -------------------------------------------------------------------------
__global__ __launch_bounds__(256) void k_wh(const u16* __restrict__ hbf,
                                            const u16* __restrict__ wt,
                                            const float* __restrict__ l,
                                            u16* __restrict__ whT) {
  __shared__ __attribute__((aligned(16))) u16 As[2][64][64];
  __shared__ __attribute__((aligned(16))) u16 Bs[2][64][64];
  const int bid = blockIdx.x;
  const int L = (bid & 7) * 128 + (bid >> 3);
  const int it = L >> 3, ft = L & 7;
  const int iG0 = it * 64;
  const int b = iG0 >> 11, icol0 = iG0 & (NN - 1);
  const int f0 = ft * 64;
  const int tid = threadIdx.x, wave = tid >> 6, lane = tid & 63;
  const int wm = (wave >> 1) * 32, wn = (wave & 1) * 32;

  const int srow = lane >> 3;
  const int scol = (((lane & 7) ^ (srow & 7)) << 3);
  const u16* gA0 = wt + ((size_t)(f0 + wave * 16 + srow)) * FF + scol;
  const u16* gB0 = hbf + ((size_t)(iG0 + wave * 16 + srow)) * FF + scol;

  f32x4 acc[2][2];
#pragma unroll
  for (int x = 0; x < 2; x++)
#pragma unroll
    for (int y = 0; y < 2; y++) acc[x][y] = f32x4{0.f, 0.f, 0.f, 0.f};

  auto STAGE = [&](int buf, int off16) {
#pragma unroll
    for (int p = 0; p < 2; p++)
      __builtin_amdgcn_global_load_lds(
          (const __attribute__((address_space(1))) void*)(gA0 + (size_t)p * 8 * FF + off16),
          (__attribute__((address_space(3))) void*)(&As[buf][wave * 16 + p * 8][0]), 16, 0, 0);
#pragma unroll
    for (int p = 0; p < 2; p++)
      __builtin_amdgcn_global_load_lds(
          (const __attribute__((address_space(1))) void*)(gB0 + (size_t)p * 8 * FF + off16),
          (__attribute__((address_space(3))) void*)(&Bs[buf][wave * 16 + p * 8][0]), 16, 0, 0);
  };

  STAGE(0, 0);

  int cur = 0;
  const int r = lane & 15, kq = lane >> 4;
  const int sx = (r & 7) << 3;
  for (int t = 0; t < 8; t++) {
    if (t < 7) {
      STAGE(cur ^ 1, (t + 1) * 64);
      asm volatile("s_waitcnt vmcnt(4)" ::: "memory");
    } else {
      asm volatile("s_waitcnt vmcnt(0)" ::: "memory");
    }
    __builtin_amdgcn_s_barrier();
#pragma unroll
    for (int kk = 0; kk < 2; kk++) {
      bf16x8 af[2], bv[2];
#pragma unroll
      for (int mi = 0; mi < 2; mi++)
        af[mi] = *(const bf16x8*)(&As[cur][wm + mi * 16 + r][(kk * 32 + kq * 8) ^ sx]);
#pragma unroll
      for (int ni = 0; ni < 2; ni++)
        bv[ni] = *(const bf16x8*)(&Bs[cur][wn + ni * 16 + r][(kk * 32 + kq * 8) ^ sx]);
#pragma unroll
      for (int mi = 0; mi < 2; mi++)
#pragma unroll
        for (int ni = 0; ni < 2; ni++)
          acc[mi][ni] = __builtin_amdgcn_mfma_f32_16x16x32_bf16(af[mi], bv[ni], acc[mi][ni], 0, 0, 0);
    }
    __builtin_amdgcn_s_barrier();
    cur ^= 1;
  }

  const int rg = lane >> 4;
#pragma unroll
  for (int ni = 0; ni < 2; ni++) {
    const int icol = icol0 + wn + ni * 16 + r;
    const float rl = __builtin_amdgcn_rcpf(l[b * NN + icol]);
#pragma unroll
    for (int mi = 0; mi < 2; mi++) {
#pragma unroll
      for (int rr = 0; rr < 4; rr++) {
        const int f = f0 + wm + mi * 16 + rg * 4 + rr;
        whT[((size_t)b * FF + f) * NN + icol] = f2bf(acc[mi][ni][rr] * rl);
      }
    }
  }
}

// -------------------------------------------------------------------------
// K4: out = leaky( P_u @ Wh' ) — bf16 GEMM, TRIPLE-buffered (depth-2 prefetch).
// BM=128, BN=64, BK=64; 512 threads (8 waves, 32x32); grid 512 (2/CU);
// T2 swizzle; steady-state vmcnt(6) = 2 stages in flight.
// -------------------------------------------------------------------------
__global__ __launch_bounds__(512) void k_out(const u16* __restrict__ P,
                                             const u16* __restrict__ whS,
                                             float* __restrict__ out) {
  __shared__ __attribute__((aligned(16))) u16 As[3][128][64];  // 48 KB
  __shared__ __attribute__((aligned(16))) u16 Bs[3][64][64];   // 24 KB
  const int bid = blockIdx.x;
  const int L = (bid & 7) * 64 + (bid >> 3);  // XCD-chunked, bijective
  const int b = L >> 7, it = (L >> 3) & 15, ft = L & 7;
  const int i0 = it * 128, f0 = ft * 64;
  const int tid = threadIdx.x, wave = tid >> 6, lane = tid & 63;
  const int wm = (wave >> 1) * 32, wn = (wave & 1) * 32;

  const int srow = lane >> 3;
  const int scol = (((lane & 7) ^ (srow & 7)) << 3);  // u16 units
  const u16* gA0 = P + ((size_t)(b * NN + i0 + wave * 16 + srow)) * NN + scol;
  const u16* gB0 = whS + ((size_t)(b * FF + f0 + wave * 8 + srow)) * NN + scol;

  f32x4 acc[2][2];
#pragma unroll
  for (int x = 0; x < 2; x++)
#pragma unroll
    for (int y = 0; y < 2; y++) acc[x][y] = f32x4{0.f, 0.f, 0.f, 0.f};

  auto STAGE = [&](int buf, int off16) {
#pragma unroll
    for (int p = 0; p < 2; p++)
      __builtin_amdgcn_global_load_lds(
          (const __attribute__((address_space(1))) void*)(gA0 + (size_t)p * 8 * NN + off16),
          (__attribute__((address_space(3))) void*)(&As[buf][wave * 16 + p * 8][0]), 16, 0, 0);
    __builtin_amdgcn_global_load_lds(
        (const __attribute__((address_space(1))) void*)(gB0 + off16),
        (__attribute__((address_space(3))) void*)(&Bs[buf][wave * 8][0]), 16, 0, 0);
  };

  STAGE(0, 0);        // tile 0 -> buf 0
  STAGE(1, 64);       // tile 1 -> buf 1

  int cur = 0;        // buffer holding tile t
  const int r = lane & 15, kq = lane >> 4;
  const int sx = (r & 7) << 3;  // read-side XOR (u16 units)
  for (int t = 0; t < 32; t++) {
    if (t <= 29) {
      int nb = cur - 1; if (nb < 0) nb += 3;   // (t+2) % 3
      STAGE(nb, (t + 2) * 64);
      asm volatile("s_waitcnt vmcnt(6)" ::: "memory");  // tiles t+1,t+2 in flight; t landed
    } else if (t == 30) {
      asm volatile("s_waitcnt vmcnt(3)" ::: "memory");  // tile 31 in flight
    } else {
      asm volatile("s_waitcnt vmcnt(0)" ::: "memory");
    }
    __builtin_amdgcn_s_barrier();
#pragma unroll
    for (int kk = 0; kk < 2; kk++) {
      bf16x8 af[2], bv[2];
#pragma unroll
      for (int mi = 0; mi < 2; mi++)
        af[mi] = *(const bf16x8*)(&As[cur][wm + mi * 16 + r][(kk * 32 + kq * 8) ^ sx]);
#pragma unroll
      for (int ni = 0; ni < 2; ni++)
        bv[ni] = *(const bf16x8*)(&Bs[cur][wn + ni * 16 + r][(kk * 32 + kq * 8) ^ sx]);
#pragma unroll
      for (int mi = 0; mi < 2; mi++)
#pragma unroll
        for (int ni = 0; ni < 2; ni++)
          acc[mi][ni] = __builtin_amdgcn_mfma_f32_16x16x32_bf16(af[mi], bv[ni], acc[mi][ni], 0, 0, 0);
    }
    __builtin_amdgcn_s_barrier();  // close reads of buf[cur] before its overwrite next iter
    cur = (cur == 2) ? 0 : cur + 1;
  }

  const int rg = lane >> 4;
#pragma unroll
  for (int mi = 0; mi < 2; mi++)
#pragma unroll
    for (int ni = 0; ni < 2; ni++) {
      const int f = f0 + wn + ni * 16 + r;
#pragma unroll
      for (int rr = 0; rr < 4; rr++) {
        const int i = i0 + wm + mi * 16 + rg * 4 + rr;
        out[((size_t)b * NN + i) * FF + f] = leaky(acc[mi][ni][rr]);
      }
    }
}

extern "C" void kernel_launch(void* const* d_in, const int* in_sizes, int n_in,
                              void* d_out, int out_size, void* d_ws, size_t ws_size,
                              hipStream_t stream) {
  const float* h = (const float*)d_in[0];
  const float* W = (const float*)d_in[1];
  const float* a = (const float*)d_in[2];
  const int* adj = (const int*)d_in[3];
  float* out = (float*)d_out;

  char* ws = (char*)d_ws;
  u16* whT = (u16*)ws;                                    // 8 MiB [b][f][i]
  float* lpart = (float*)ws;                              // 8 MiB (256 chunks), ALIASES whT:
                                                          // consumed by k_lred before k_wh writes whT
  u16* P = (u16*)(ws + (size_t)8388608);                  // 33.5 MiB [b][i][j]
  float* s1 = (float*)(ws + (size_t)8388608 + 33554432);  // 32 KiB
  float* s2 = s1 + BB * NN;                               // 32 KiB
  float* lsum = s2 + BB * NN;                             // 32 KiB
  float* wa1 = lsum + BB * NN;                            // 2 KiB
  float* wa2 = wa1 + FF;                                  // 2 KiB
  u16* hbf = (u16*)(wa2 + FF);                            // 8 MiB [row][f]
  u16* wt = hbf + (size_t)BB * NN * FF;                   // 512 KiB [f][k]

  k_wawt<<<dim3(192), 256, 0, stream>>>(W, a, wa1, wa2, wt);
  k_s<<<dim3(2048), 256, 0, stream>>>(h, wa1, wa2, s1, s2, hbf);
  k_l<<<dim3(128, 4), 512, 0, stream>>>(adj, s1, s2, lpart, P);
  k_lred<<<dim3(256), 256, 0, stream>>>(lpart, lsum);
  k_wh<<<dim3(1024), 256, 0, stream>>>(hbf, wt, lsum, whT);
  k_out<<<dim3(512), 512, 0, stream>>>(P, whT, out);
}

// Round 17
// 73.840 us; speedup vs baseline: 1.0030x; 1.0030x over previous
//
#include <hip/hip_runtime.h>

#define BB 4
#define NN 2048
#define FF 512
#define ALPHA 0.2f

typedef unsigned short u16;
typedef unsigned int u32;
typedef __attribute__((ext_vector_type(8))) short bf16x8;
typedef __attribute__((ext_vector_type(4))) float f32x4;

__device__ __forceinline__ u16 f2bf(float x) {
  union { float f; u32 u; } v; v.f = x;
  u32 r = v.u + 0x7fffu + ((v.u >> 16) & 1u);
  return (u16)(r >> 16);
}
__device__ __forceinline__ float leaky(float x) { return x >= 0.f ? x : ALPHA * x; }

// -------------------------------------------------------------------------
// K0: fused  (bid < 64)  wt[f][k] = bf16(W[k][f])   64x64 LDS transpose
//            (bid >= 64) wa1/wa2 = W^T @ a halves   4 rows per block
// -------------------------------------------------------------------------
__global__ __launch_bounds__(256) void k_wawt(const float* __restrict__ W,
                                              const float* __restrict__ a,
                                              float* __restrict__ wa1,
                                              float* __restrict__ wa2,
                                              u16* __restrict__ wt) {
  __shared__ float T[64][65];
  const int tid = threadIdx.x;
  if (blockIdx.x < 64) {
    const int k0 = (blockIdx.x & 7) * 64, f0 = (blockIdx.x >> 3) * 64;
    const int c = tid & 15, r0 = tid >> 4;
#pragma unroll
    for (int p = 0; p < 4; p++) {
      const int k = r0 + p * 16;
      float4 v = *(const float4*)(W + (size_t)(k0 + k) * FF + f0 + c * 4);
      T[c * 4 + 0][k] = v.x;
      T[c * 4 + 1][k] = v.y;
      T[c * 4 + 2][k] = v.z;
      T[c * 4 + 3][k] = v.w;
    }
    __syncthreads();
    const int kc = tid & 7, fr0 = tid >> 3;
#pragma unroll
    for (int p = 0; p < 2; p++) {
      const int f = fr0 + p * 32;
      union { uint4 q; u16 s[8]; } o;
#pragma unroll
      for (int q = 0; q < 8; q++) o.s[q] = f2bf(T[f][kc * 8 + q]);
      *(uint4*)(wt + (size_t)(f0 + f) * FF + k0 + kc * 8) = o.q;
    }
  } else {
    const int wave = tid >> 6, lane = tid & 63;
    const int k = (blockIdx.x - 64) * 4 + wave;
    const int f0 = lane * 8;
    float4 w0 = *(const float4*)(W + (size_t)k * FF + f0);
    float4 w1 = *(const float4*)(W + (size_t)k * FF + f0 + 4);
    float4 p0 = *(const float4*)(a + f0);
    float4 p1 = *(const float4*)(a + f0 + 4);
    float4 q0 = *(const float4*)(a + FF + f0);
    float4 q1 = *(const float4*)(a + FF + f0 + 4);
    float d1 = w0.x*p0.x + w0.y*p0.y + w0.z*p0.z + w0.w*p0.w
             + w1.x*p1.x + w1.y*p1.y + w1.z*p1.z + w1.w*p1.w;
    float d2 = w0.x*q0.x + w0.y*q0.y + w0.z*q0.z + w0.w*q0.w
             + w1.x*q1.x + w1.y*q1.y + w1.z*q1.z + w1.w*q1.w;
#pragma unroll
    for (int o = 32; o; o >>= 1) { d1 += __shfl_xor(d1, o); d2 += __shfl_xor(d2, o); }
    if (lane == 0) { wa1[k] = d1; wa2[k] = d2; }
  }
}

// -------------------------------------------------------------------------
// K0b: s1/s2 = h·wa1 / h·wa2  (fp32)  +  emit hbf = bf16(h)  (coalesced)
// -------------------------------------------------------------------------
__global__ __launch_bounds__(256) void k_s(const float* __restrict__ h,
                                           const float* __restrict__ wa1,
                                           const float* __restrict__ wa2,
                                           float* __restrict__ s1,
                                           float* __restrict__ s2,
                                           u16* __restrict__ hbf) {
  const int wave = threadIdx.x >> 6, lane = threadIdx.x & 63;
  const int row = blockIdx.x * 4 + wave;  // 0..8191
  const int f0 = lane * 8;
  float4 h0 = *(const float4*)(h + (size_t)row * FF + f0);
  float4 h1 = *(const float4*)(h + (size_t)row * FF + f0 + 4);
  float4 p0 = *(const float4*)(wa1 + f0);
  float4 p1 = *(const float4*)(wa1 + f0 + 4);
  float4 q0 = *(const float4*)(wa2 + f0);
  float4 q1 = *(const float4*)(wa2 + f0 + 4);
  union { uint4 q; u16 s[8]; } ob;
  ob.s[0] = f2bf(h0.x); ob.s[1] = f2bf(h0.y); ob.s[2] = f2bf(h0.z); ob.s[3] = f2bf(h0.w);
  ob.s[4] = f2bf(h1.x); ob.s[5] = f2bf(h1.y); ob.s[6] = f2bf(h1.z); ob.s[7] = f2bf(h1.w);
  *(uint4*)(hbf + (size_t)row * FF + f0) = ob.q;
  float d1 = h0.x*p0.x + h0.y*p0.y + h0.z*p0.z + h0.w*p0.w
           + h1.x*p1.x + h1.y*p1.y + h1.z*p1.z + h1.w*p1.w;
  float d2 = h0.x*q0.x + h0.y*q0.y + h0.z*q0.z + h0.w*q0.w
           + h1.x*q1.x + h1.y*q1.y + h1.z*q1.z + h1.w*q1.w;
#pragma unroll
  for (int o = 32; o; o >>= 1) { d1 += __shfl_xor(d1, o); d2 += __shfl_xor(d2, o); }
  if (lane == 0) { s1[row] = d1; s2[row] = d2; }
}

// -------------------------------------------------------------------------
// K2: stream adj once; emit P_u[b][i][j] bf16 (16B stores) + lpart partials.
// v4: grid (256,4) = 1024 blocks = 4 blocks/CU = 32 waves/CU.
// 8 rows/block in 2 groups of 4; LDS cross-group reduce -> 1 chunk/block.
// -------------------------------------------------------------------------
__global__ __launch_bounds__(512) void k_l(const int* __restrict__ adj,
                                           const float* __restrict__ s1,
                                           const float* __restrict__ s2,
                                           float* __restrict__ lpart,
                                           u16* __restrict__ P) {
  __shared__ float red[256][8];
  const int b = blockIdx.y, t = threadIdx.x;
  const int rh = t >> 8;                 // row group: 0/1
  const int tj = t & 255, j8 = tj * 8;
  const int i0 = blockIdx.x * 8 + rh * 4;
  float s2v[8];
  *(float4*)(&s2v[0]) = *(const float4*)(s2 + b * NN + j8);
  *(float4*)(&s2v[4]) = *(const float4*)(s2 + b * NN + j8 + 4);
  float accv[8];
#pragma unroll
  for (int k = 0; k < 8; k++) accv[k] = 0.f;
  const int* abase = adj + ((size_t)b * NN + i0) * NN + j8;
  u16* pbase = P + ((size_t)b * NN + i0) * NN + j8;
#pragma unroll
  for (int i = 0; i < 4; i++) {
    int4 A0 = *(const int4*)(abase + (size_t)i * NN);
    int4 A1 = *(const int4*)(abase + (size_t)i * NN + 4);
    const float s1i = s1[b * NN + i0 + i];
    int av[8] = {A0.x, A0.y, A0.z, A0.w, A1.x, A1.y, A1.z, A1.w};
    union { uint4 q; u16 s[8]; } o;
#pragma unroll
    for (int k = 0; k < 8; k++) {
      float p = (av[k] > 0) ? __expf(leaky(s1i + s2v[k])) : 0.f;
      accv[k] += p;
      o.s[k] = f2bf(p);
    }
    *(uint4*)(pbase + (size_t)i * NN) = o.q;
  }
  if (rh == 1) {
#pragma unroll
    for (int k = 0; k < 8; k++) red[tj][k] = accv[k];
  }
  __syncthreads();
  if (rh == 0) {
#pragma unroll
    for (int k = 0; k < 8; k++) accv[k] += red[tj][k];
    float* lp = lpart + (size_t)blockIdx.x * (BB * NN) + b * NN + j8;
    *(float4*)lp = *(float4*)(&accv[0]);
    *(float4*)(lp + 4) = *(float4*)(&accv[4]);
  }
}

// -------------------------------------------------------------------------
// K2b: l[idx] = sum over 256 chunks of lpart[c][idx].
// grid 256 blocks; block owns 32 idx; 8-way chunk split + LDS reduce.
// -------------------------------------------------------------------------
__global__ __launch_bounds__(256) void k_lred(const float* __restrict__ lpart,
                                              float* __restrict__ l) {
  __shared__ float red[8][32];
  const int t = threadIdx.x;
  const int io = t & 31, cg = t >> 5;        // idx-offset, chunk-group
  const int idx = blockIdx.x * 32 + io;
  float s = 0.f;
#pragma unroll 8
  for (int c = cg; c < 256; c += 8) s += lpart[(size_t)c * (BB * NN) + idx];
  red[cg][io] = s;
  __syncthreads();
  if (t < 32) {
    float r = 0.f;
#pragma unroll
    for (int g = 0; g < 8; g++) r += red[g][t];
    l[blockIdx.x * 32 + t] = r;
  }
}

// -------------------------------------------------------------------------
// K3: whT[b][f][i] = bf16( (h@W)[i][f] * 1/l[b][i] ) — pipelined GEMM.
// (unchanged)
// -------------------------------------------------------------------------
__global__ __launch_bounds__(256) void k_wh(const u16* __restrict__ hbf,
                                            const u16* __restrict__ wt,
                                            const float* __restrict__ l,
                                            u16* __restrict__ whT) {
  __shared__ __attribute__((aligned(16))) u16 As[2][64][64];
  __shared__ __attribute__((aligned(16))) u16 Bs[2][64][64];
  const int bid = blockIdx.x;
  const int L = (bid & 7) * 128 + (bid >> 3);
  const int it = L >> 3, ft = L & 7;
  const int iG0 = it * 64;
  const int b = iG0 >> 11, icol0 = iG0 & (NN - 1);
  const int f0 = ft * 64;
  const int tid = threadIdx.x, wave = tid >> 6, lane = tid & 63;
  const int wm = (wave >> 1) * 32, wn = (wave & 1) * 32;

  const int srow = lane >> 3;
  const int scol = (((lane & 7) ^ (srow & 7)) << 3);
  const u16* gA0 = wt + ((size_t)(f0 + wave * 16 + srow)) * FF + scol;
  const u16* gB0 = hbf + ((size_t)(iG0 + wave * 16 + srow)) * FF + scol;

  f32x4 acc[2][2];
#pragma unroll
  for (int x = 0; x < 2; x++)
#pragma unroll
    for (int y = 0; y < 2; y++) acc[x][y] = f32x4{0.f, 0.f, 0.f, 0.f};

  auto STAGE = [&](int buf, int off16) {
#pragma unroll
    for (int p = 0; p < 2; p++)
      __builtin_amdgcn_global_load_lds(
          (const __attribute__((address_space(1))) void*)(gA0 + (size_t)p * 8 * FF + off16),
          (__attribute__((address_space(3))) void*)(&As[buf][wave * 16 + p * 8][0]), 16, 0, 0);
#pragma unroll
    for (int p = 0; p < 2; p++)
      __builtin_amdgcn_global_load_lds(
          (const __attribute__((address_space(1))) void*)(gB0 + (size_t)p * 8 * FF + off16),
          (__attribute__((address_space(3))) void*)(&Bs[buf][wave * 16 + p * 8][0]), 16, 0, 0);
  };

  STAGE(0, 0);

  int cur = 0;
  const int r = lane & 15, kq = lane >> 4;
  const int sx = (r & 7) << 3;
  for (int t = 0; t < 8; t++) {
    if (t < 7) {
      STAGE(cur ^ 1, (t + 1) * 64);
      asm volatile("s_waitcnt vmcnt(4)" ::: "memory");
    } else {
      asm volatile("s_waitcnt vmcnt(0)" ::: "memory");
    }
    __builtin_amdgcn_s_barrier();
#pragma unroll
    for (int kk = 0; kk < 2; kk++) {
      bf16x8 af[2], bv[2];
#pragma unroll
      for (int mi = 0; mi < 2; mi++)
        af[mi] = *(const bf16x8*)(&As[cur][wm + mi * 16 + r][(kk * 32 + kq * 8) ^ sx]);
#pragma unroll
      for (int ni = 0; ni < 2; ni++)
        bv[ni] = *(const bf16x8*)(&Bs[cur][wn + ni * 16 + r][(kk * 32 + kq * 8) ^ sx]);
#pragma unroll
      for (int mi = 0; mi < 2; mi++)
#pragma unroll
        for (int ni = 0; ni < 2; ni++)
          acc[mi][ni] = __builtin_amdgcn_mfma_f32_16x16x32_bf16(af[mi], bv[ni], acc[mi][ni], 0, 0, 0);
    }
    __builtin_amdgcn_s_barrier();
    cur ^= 1;
  }

  const int rg = lane >> 4;
#pragma unroll
  for (int ni = 0; ni < 2; ni++) {
    const int icol = icol0 + wn + ni * 16 + r;
    const float rl = __builtin_amdgcn_rcpf(l[b * NN + icol]);
#pragma unroll
    for (int mi = 0; mi < 2; mi++) {
#pragma unroll
      for (int rr = 0; rr < 4; rr++) {
        const int f = f0 + wm + mi * 16 + rg * 4 + rr;
        whT[((size_t)b * FF + f) * NN + icol] = f2bf(acc[mi][ni][rr] * rl);
      }
    }
  }
}

// -------------------------------------------------------------------------
// K4: out = leaky( P_u @ Wh' ) — bf16 GEMM, TRIPLE-buffered (depth-2).
// (unchanged from round 16)
// -------------------------------------------------------------------------
__global__ __launch_bounds__(512) void k_out(const u16* __restrict__ P,
                                             const u16* __restrict__ whS,
                                             float* __restrict__ out) {
  __shared__ __attribute__((aligned(16))) u16 As[3][128][64];  // 48 KB
  __shared__ __attribute__((aligned(16))) u16 Bs[3][64][64];   // 24 KB
  const int bid = blockIdx.x;
  const int L = (bid & 7) * 64 + (bid >> 3);  // XCD-chunked, bijective
  const int b = L >> 7, it = (L >> 3) & 15, ft = L & 7;
  const int i0 = it * 128, f0 = ft * 64;
  const int tid = threadIdx.x, wave = tid >> 6, lane = tid & 63;
  const int wm = (wave >> 1) * 32, wn = (wave & 1) * 32;

  const int srow = lane >> 3;
  const int scol = (((lane & 7) ^ (srow & 7)) << 3);  // u16 units
  const u16* gA0 = P + ((size_t)(b * NN + i0 + wave * 16 + srow)) * NN + scol;
  const u16* gB0 = whS + ((size_t)(b * FF + f0 + wave * 8 + srow)) * NN + scol;

  f32x4 acc[2][2];
#pragma unroll
  for (int x = 0; x < 2; x++)
#pragma unroll
    for (int y = 0; y < 2; y++) acc[x][y] = f32x4{0.f, 0.f, 0.f, 0.f};

  auto STAGE = [&](int buf, int off16) {
#pragma unroll
    for (int p = 0; p < 2; p++)
      __builtin_amdgcn_global_load_lds(
          (const __attribute__((address_space(1))) void*)(gA0 + (size_t)p * 8 * NN + off16),
          (__attribute__((address_space(3))) void*)(&As[buf][wave * 16 + p * 8][0]), 16, 0, 0);
    __builtin_amdgcn_global_load_lds(
        (const __attribute__((address_space(1))) void*)(gB0 + off16),
        (__attribute__((address_space(3))) void*)(&Bs[buf][wave * 8][0]), 16, 0, 0);
  };

  STAGE(0, 0);        // tile 0 -> buf 0
  STAGE(1, 64);       // tile 1 -> buf 1

  int cur = 0;
  const int r = lane & 15, kq = lane >> 4;
  const int sx = (r & 7) << 3;
  for (int t = 0; t < 32; t++) {
    if (t <= 29) {
      int nb = cur - 1; if (nb < 0) nb += 3;   // (t+2) % 3
      STAGE(nb, (t + 2) * 64);
      asm volatile("s_waitcnt vmcnt(6)" ::: "memory");
    } else if (t == 30) {
      asm volatile("s_waitcnt vmcnt(3)" ::: "memory");
    } else {
      asm volatile("s_waitcnt vmcnt(0)" ::: "memory");
    }
    __builtin_amdgcn_s_barrier();
#pragma unroll
    for (int kk = 0; kk < 2; kk++) {
      bf16x8 af[2], bv[2];
#pragma unroll
      for (int mi = 0; mi < 2; mi++)
        af[mi] = *(const bf16x8*)(&As[cur][wm + mi * 16 + r][(kk * 32 + kq * 8) ^ sx]);
#pragma unroll
      for (int ni = 0; ni < 2; ni++)
        bv[ni] = *(const bf16x8*)(&Bs[cur][wn + ni * 16 + r][(kk * 32 + kq * 8) ^ sx]);
#pragma unroll
      for (int mi = 0; mi < 2; mi++)
#pragma unroll
        for (int ni = 0; ni < 2; ni++)
          acc[mi][ni] = __builtin_amdgcn_mfma_f32_16x16x32_bf16(af[mi], bv[ni], acc[mi][ni], 0, 0, 0);
    }
    __builtin_amdgcn_s_barrier();
    cur = (cur == 2) ? 0 : cur + 1;
  }

  const int rg = lane >> 4;
#pragma unroll
  for (int mi = 0; mi < 2; mi++)
#pragma unroll
    for (int ni = 0; ni < 2; ni++) {
      const int f = f0 + wn + ni * 16 + r;
#pragma unroll
      for (int rr = 0; rr < 4; rr++) {
        const int i = i0 + wm + mi * 16 + rg * 4 + rr;
        out[((size_t)b * NN + i) * FF + f] = leaky(acc[mi][ni][rr]);
      }
    }
}

extern "C" void kernel_launch(void* const* d_in, const int* in_sizes, int n_in,
                              void* d_out, int out_size, void* d_ws, size_t ws_size,
                              hipStream_t stream) {
  const float* h = (const float*)d_in[0];
  const float* W = (const float*)d_in[1];
  const float* a = (const float*)d_in[2];
  const int* adj = (const int*)d_in[3];
  float* out = (float*)d_out;

  char* ws = (char*)d_ws;
  u16* whT = (u16*)ws;                                    // 8 MiB [b][f][i]
  float* lpart = (float*)ws;                              // 8 MiB (256 chunks), ALIASES whT:
                                                          // consumed by k_lred before k_wh writes whT
  u16* P = (u16*)(ws + (size_t)8388608);                  // 33.5 MiB [b][i][j]
  float* s1 = (float*)(ws + (size_t)8388608 + 33554432);  // 32 KiB
  float* s2 = s1 + BB * NN;                               // 32 KiB
  float* lsum = s2 + BB * NN;                             // 32 KiB
  float* wa1 = lsum + BB * NN;                            // 2 KiB
  float* wa2 = wa1 + FF;                                  // 2 KiB
  u16* hbf = (u16*)(wa2 + FF);                            // 8 MiB [row][f]
  u16* wt = hbf + (size_t)BB * NN * FF;                   // 512 KiB [f][k]

  k_wawt<<<dim3(192), 256, 0, stream>>>(W, a, wa1, wa2, wt);
  k_s<<<dim3(2048), 256, 0, stream>>>(h, wa1, wa2, s1, s2, hbf);
  k_l<<<dim3(256, 4), 512, 0, stream>>>(adj, s1, s2, lpart, P);
  k_lred<<<dim3(256), 256, 0, stream>>>(lpart, lsum);
  k_wh<<<dim3(1024), 256, 0, stream>>>(hbf, wt, lsum, whT);
  k_out<<<dim3(512), 512, 0, stream>>>(P, whT, out);
}

// Round 18
// 70.895 us; speedup vs baseline: 1.0446x; 1.0415x over previous
//
#include <hip/hip_runtime.h>

#define BB 4
#define NN 2048
#define FF 512
#define ALPHA 0.2f

typedef unsigned short u16;
typedef unsigned int u32;
typedef __attribute__((ext_vector_type(8))) short bf16x8;
typedef __attribute__((ext_vector_type(4))) float f32x4;

__device__ __forceinline__ u16 f2bf(float x) {
  union { float f; u32 u; } v; v.f = x;
  u32 r = v.u + 0x7fffu + ((v.u >> 16) & 1u);
  return (u16)(r >> 16);
}
__device__ __forceinline__ float leaky(float x) { return x >= 0.f ? x : ALPHA * x; }

// -------------------------------------------------------------------------
// K0: fused  (bid < 64)  wt[f][k] = bf16(W[k][f])   64x64 LDS transpose
//            (bid >= 64) wa1/wa2 = W^T @ a halves   4 rows per block
// -------------------------------------------------------------------------
__global__ __launch_bounds__(256) void k_wawt(const float* __restrict__ W,
                                              const float* __restrict__ a,
                                              float* __restrict__ wa1,
                                              float* __restrict__ wa2,
                                              u16* __restrict__ wt) {
  __shared__ float T[64][65];
  const int tid = threadIdx.x;
  if (blockIdx.x < 64) {
    const int k0 = (blockIdx.x & 7) * 64, f0 = (blockIdx.x >> 3) * 64;
    const int c = tid & 15, r0 = tid >> 4;
#pragma unroll
    for (int p = 0; p < 4; p++) {
      const int k = r0 + p * 16;
      float4 v = *(const float4*)(W + (size_t)(k0 + k) * FF + f0 + c * 4);
      T[c * 4 + 0][k] = v.x;
      T[c * 4 + 1][k] = v.y;
      T[c * 4 + 2][k] = v.z;
      T[c * 4 + 3][k] = v.w;
    }
    __syncthreads();
    const int kc = tid & 7, fr0 = tid >> 3;
#pragma unroll
    for (int p = 0; p < 2; p++) {
      const int f = fr0 + p * 32;
      union { uint4 q; u16 s[8]; } o;
#pragma unroll
      for (int q = 0; q < 8; q++) o.s[q] = f2bf(T[f][kc * 8 + q]);
      *(uint4*)(wt + (size_t)(f0 + f) * FF + k0 + kc * 8) = o.q;
    }
  } else {
    const int wave = tid >> 6, lane = tid & 63;
    const int k = (blockIdx.x - 64) * 4 + wave;
    const int f0 = lane * 8;
    float4 w0 = *(const float4*)(W + (size_t)k * FF + f0);
    float4 w1 = *(const float4*)(W + (size_t)k * FF + f0 + 4);
    float4 p0 = *(const float4*)(a + f0);
    float4 p1 = *(const float4*)(a + f0 + 4);
    float4 q0 = *(const float4*)(a + FF + f0);
    float4 q1 = *(const float4*)(a + FF + f0 + 4);
    float d1 = w0.x*p0.x + w0.y*p0.y + w0.z*p0.z + w0.w*p0.w
             + w1.x*p1.x + w1.y*p1.y + w1.z*p1.z + w1.w*p1.w;
    float d2 = w0.x*q0.x + w0.y*q0.y + w0.z*q0.z + w0.w*q0.w
             + w1.x*q1.x + w1.y*q1.y + w1.z*q1.z + w1.w*q1.w;
#pragma unroll
    for (int o = 32; o; o >>= 1) { d1 += __shfl_xor(d1, o); d2 += __shfl_xor(d2, o); }
    if (lane == 0) { wa1[k] = d1; wa2[k] = d2; }
  }
}

// -------------------------------------------------------------------------
// K0b: s1/s2 = h·wa1 / h·wa2  (fp32)  +  emit hbf = bf16(h)  (coalesced)
// -------------------------------------------------------------------------
__global__ __launch_bounds__(256) void k_s(const float* __restrict__ h,
                                           const float* __restrict__ wa1,
                                           const float* __restrict__ wa2,
                                           float* __restrict__ s1,
                                           float* __restrict__ s2,
                                           u16* __restrict__ hbf) {
  const int wave = threadIdx.x >> 6, lane = threadIdx.x & 63;
  const int row = blockIdx.x * 4 + wave;  // 0..8191
  const int f0 = lane * 8;
  float4 h0 = *(const float4*)(h + (size_t)row * FF + f0);
  float4 h1 = *(const float4*)(h + (size_t)row * FF + f0 + 4);
  float4 p0 = *(const float4*)(wa1 + f0);
  float4 p1 = *(const float4*)(wa1 + f0 + 4);
  float4 q0 = *(const float4*)(wa2 + f0);
  float4 q1 = *(const float4*)(wa2 + f0 + 4);
  union { uint4 q; u16 s[8]; } ob;
  ob.s[0] = f2bf(h0.x); ob.s[1] = f2bf(h0.y); ob.s[2] = f2bf(h0.z); ob.s[3] = f2bf(h0.w);
  ob.s[4] = f2bf(h1.x); ob.s[5] = f2bf(h1.y); ob.s[6] = f2bf(h1.z); ob.s[7] = f2bf(h1.w);
  *(uint4*)(hbf + (size_t)row * FF + f0) = ob.q;
  float d1 = h0.x*p0.x + h0.y*p0.y + h0.z*p0.z + h0.w*p0.w
           + h1.x*p1.x + h1.y*p1.y + h1.z*p1.z + h1.w*p1.w;
  float d2 = h0.x*q0.x + h0.y*q0.y + h0.z*q0.z + h0.w*q0.w
           + h1.x*q1.x + h1.y*q1.y + h1.z*q1.z + h1.w*q1.w;
#pragma unroll
  for (int o = 32; o; o >>= 1) { d1 += __shfl_xor(d1, o); d2 += __shfl_xor(d2, o); }
  if (lane == 0) { s1[row] = d1; s2[row] = d2; }
}

// -------------------------------------------------------------------------
// K2: stream adj once; emit P_u[b][i][j] bf16 (16B stores) + lpart partials.
// grid (256,4) = 1024 blocks = 4 blocks/CU; 8 rows/block in 2 groups of 4.
// -------------------------------------------------------------------------
__global__ __launch_bounds__(512) void k_l(const int* __restrict__ adj,
                                           const float* __restrict__ s1,
                                           const float* __restrict__ s2,
                                           float* __restrict__ lpart,
                                           u16* __restrict__ P) {
  __shared__ float red[256][8];
  const int b = blockIdx.y, t = threadIdx.x;
  const int rh = t >> 8;                 // row group: 0/1
  const int tj = t & 255, j8 = tj * 8;
  const int i0 = blockIdx.x * 8 + rh * 4;
  float s2v[8];
  *(float4*)(&s2v[0]) = *(const float4*)(s2 + b * NN + j8);
  *(float4*)(&s2v[4]) = *(const float4*)(s2 + b * NN + j8 + 4);
  float accv[8];
#pragma unroll
  for (int k = 0; k < 8; k++) accv[k] = 0.f;
  const int* abase = adj + ((size_t)b * NN + i0) * NN + j8;
  u16* pbase = P + ((size_t)b * NN + i0) * NN + j8;
#pragma unroll
  for (int i = 0; i < 4; i++) {
    int4 A0 = *(const int4*)(abase + (size_t)i * NN);
    int4 A1 = *(const int4*)(abase + (size_t)i * NN + 4);
    const float s1i = s1[b * NN + i0 + i];
    int av[8] = {A0.x, A0.y, A0.z, A0.w, A1.x, A1.y, A1.z, A1.w};
    union { uint4 q; u16 s[8]; } o;
#pragma unroll
    for (int k = 0; k < 8; k++) {
      float p = (av[k] > 0) ? __expf(leaky(s1i + s2v[k])) : 0.f;
      accv[k] += p;
      o.s[k] = f2bf(p);
    }
    *(uint4*)(pbase + (size_t)i * NN) = o.q;
  }
  if (rh == 1) {
#pragma unroll
    for (int k = 0; k < 8; k++) red[tj][k] = accv[k];
  }
  __syncthreads();
  if (rh == 0) {
#pragma unroll
    for (int k = 0; k < 8; k++) accv[k] += red[tj][k];
    float* lp = lpart + (size_t)blockIdx.x * (BB * NN) + b * NN + j8;
    *(float4*)lp = *(float4*)(&accv[0]);
    *(float4*)(lp + 4) = *(float4*)(&accv[4]);
  }
}

// -------------------------------------------------------------------------
// K2b: l[idx] = sum over 256 chunks of lpart[c][idx].
// -------------------------------------------------------------------------
__global__ __launch_bounds__(256) void k_lred(const float* __restrict__ lpart,
                                              float* __restrict__ l) {
  __shared__ float red[8][32];
  const int t = threadIdx.x;
  const int io = t & 31, cg = t >> 5;
  const int idx = blockIdx.x * 32 + io;
  float s = 0.f;
#pragma unroll 8
  for (int c = cg; c < 256; c += 8) s += lpart[(size_t)c * (BB * NN) + idx];
  red[cg][io] = s;
  __syncthreads();
  if (t < 32) {
    float r = 0.f;
#pragma unroll
    for (int g = 0; g < 8; g++) r += red[g][t];
    l[blockIdx.x * 32 + t] = r;
  }
}

// -------------------------------------------------------------------------
// K3: whT[b][f][i] = bf16( (h@W)[i][f] * 1/l[b][i] ) — pipelined GEMM.
// (unchanged)
// -------------------------------------------------------------------------
__global__ __launch_bounds__(256) void k_wh(const u16* __restrict__ hbf,
                                            const u16* __restrict__ wt,
                                            const float* __restrict__ l,
                                            u16* __restrict__ whT) {
  __shared__ __attribute__((aligned(16))) u16 As[2][64][64];
  __shared__ __attribute__((aligned(16))) u16 Bs[2][64][64];
  const int bid = blockIdx.x;
  const int L = (bid & 7) * 128 + (bid >> 3);
  const int it = L >> 3, ft = L & 7;
  const int iG0 = it * 64;
  const int b = iG0 >> 11, icol0 = iG0 & (NN - 1);
  const int f0 = ft * 64;
  const int tid = threadIdx.x, wave = tid >> 6, lane = tid & 63;
  const int wm = (wave >> 1) * 32, wn = (wave & 1) * 32;

  const int srow = lane >> 3;
  const int scol = (((lane & 7) ^ (srow & 7)) << 3);
  const u16* gA0 = wt + ((size_t)(f0 + wave * 16 + srow)) * FF + scol;
  const u16* gB0 = hbf + ((size_t)(iG0 + wave * 16 + srow)) * FF + scol;

  f32x4 acc[2][2];
#pragma unroll
  for (int x = 0; x < 2; x++)
#pragma unroll
    for (int y = 0; y < 2; y++) acc[x][y] = f32x4{0.f, 0.f, 0.f, 0.f};

  auto STAGE = [&](int buf, int off16) {
#pragma unroll
    for (int p = 0; p < 2; p++)
      __builtin_amdgcn_global_load_lds(
          (const __attribute__((address_space(1))) void*)(gA0 + (size_t)p * 8 * FF + off16),
          (__attribute__((address_space(3))) void*)(&As[buf][wave * 16 + p * 8][0]), 16, 0, 0);
#pragma unroll
    for (int p = 0; p < 2; p++)
      __builtin_amdgcn_global_load_lds(
          (const __attribute__((address_space(1))) void*)(gB0 + (size_t)p * 8 * FF + off16),
          (__attribute__((address_space(3))) void*)(&Bs[buf][wave * 16 + p * 8][0]), 16, 0, 0);
  };

  STAGE(0, 0);

  int cur = 0;
  const int r = lane & 15, kq = lane >> 4;
  const int sx = (r & 7) << 3;
  for (int t = 0; t < 8; t++) {
    if (t < 7) {
      STAGE(cur ^ 1, (t + 1) * 64);
      asm volatile("s_waitcnt vmcnt(4)" ::: "memory");
    } else {
      asm volatile("s_waitcnt vmcnt(0)" ::: "memory");
    }
    __builtin_amdgcn_s_barrier();
#pragma unroll
    for (int kk = 0; kk < 2; kk++) {
      bf16x8 af[2], bv[2];
#pragma unroll
      for (int mi = 0; mi < 2; mi++)
        af[mi] = *(const bf16x8*)(&As[cur][wm + mi * 16 + r][(kk * 32 + kq * 8) ^ sx]);
#pragma unroll
      for (int ni = 0; ni < 2; ni++)
        bv[ni] = *(const bf16x8*)(&Bs[cur][wn + ni * 16 + r][(kk * 32 + kq * 8) ^ sx]);
#pragma unroll
      for (int mi = 0; mi < 2; mi++)
#pragma unroll
        for (int ni = 0; ni < 2; ni++)
          acc[mi][ni] = __builtin_amdgcn_mfma_f32_16x16x32_bf16(af[mi], bv[ni], acc[mi][ni], 0, 0, 0);
    }
    __builtin_amdgcn_s_barrier();
    cur ^= 1;
  }

  const int rg = lane >> 4;
#pragma unroll
  for (int ni = 0; ni < 2; ni++) {
    const int icol = icol0 + wn + ni * 16 + r;
    const float rl = __builtin_amdgcn_rcpf(l[b * NN + icol]);
#pragma unroll
    for (int mi = 0; mi < 2; mi++) {
#pragma unroll
      for (int rr = 0; rr < 4; rr++) {
        const int f = f0 + wm + mi * 16 + rg * 4 + rr;
        whT[((size_t)b * FF + f) * NN + icol] = f2bf(acc[mi][ni][rr] * rl);
      }
    }
  }
}

// -------------------------------------------------------------------------
// K4: out = leaky( P_u @ Wh' ) — bf16 GEMM, 3-buffer, SINGLE barrier/iter.
// STAGE(t+2) issued AFTER the barrier+MFMA of iter t, so the one barrier
// orders last-readers(buf) before its overwrite (WAR safe by construction).
// Steady-state vmcnt(3): tile t landed, tile t+1 in flight.
// -------------------------------------------------------------------------
__global__ __launch_bounds__(512) void k_out(const u16* __restrict__ P,
                                             const u16* __restrict__ whS,
                                             float* __restrict__ out) {
  __shared__ __attribute__((aligned(16))) u16 As[3][128][64];  // 48 KB
  __shared__ __attribute__((aligned(16))) u16 Bs[3][64][64];   // 24 KB
  const int bid = blockIdx.x;
  const int L = (bid & 7) * 64 + (bid >> 3);  // XCD-chunked, bijective
  const int b = L >> 7, it = (L >> 3) & 15, ft = L & 7;
  const int i0 = it * 128, f0 = ft * 64;
  const int tid = threadIdx.x, wave = tid >> 6, lane = tid & 63;
  const int wm = (wave >> 1) * 32, wn = (wave & 1) * 32;

  const int srow = lane >> 3;
  const int scol = (((lane & 7) ^ (srow & 7)) << 3);  // u16 units
  const u16* gA0 = P + ((size_t)(b * NN + i0 + wave * 16 + srow)) * NN + scol;
  const u16* gB0 = whS + ((size_t)(b * FF + f0 + wave * 8 + srow)) * NN + scol;

  f32x4 acc[2][2];
#pragma unroll
  for (int x = 0; x < 2; x++)
#pragma unroll
    for (int y = 0; y < 2; y++) acc[x][y] = f32x4{0.f, 0.f, 0.f, 0.f};

  auto STAGE = [&](int buf, int off16) {
#pragma unroll
    for (int p = 0; p < 2; p++)
      __builtin_amdgcn_global_load_lds(
          (const __attribute__((address_space(1))) void*)(gA0 + (size_t)p * 8 * NN + off16),
          (__attribute__((address_space(3))) void*)(&As[buf][wave * 16 + p * 8][0]), 16, 0, 0);
    __builtin_amdgcn_global_load_lds(
        (const __attribute__((address_space(1))) void*)(gB0 + off16),
        (__attribute__((address_space(3))) void*)(&Bs[buf][wave * 8][0]), 16, 0, 0);
  };

  STAGE(0, 0);        // tile 0 -> buf 0
  STAGE(1, 64);       // tile 1 -> buf 1

  int cur = 0;        // buffer holding tile t
  const int r = lane & 15, kq = lane >> 4;
  const int sx = (r & 7) << 3;  // read-side XOR (u16 units)
  for (int t = 0; t < 32; t++) {
    if (t < 31) {
      asm volatile("s_waitcnt vmcnt(3)" ::: "memory");  // tile t landed; t+1 in flight
    } else {
      asm volatile("s_waitcnt vmcnt(0)" ::: "memory");
    }
    __builtin_amdgcn_s_barrier();  // (a) buf[cur] staged by all waves
                                   // (b) closes iter t-1's reads of buf[(t+1)%3's target]
#pragma unroll
    for (int kk = 0; kk < 2; kk++) {
      bf16x8 af[2], bv[2];
#pragma unroll
      for (int mi = 0; mi < 2; mi++)
        af[mi] = *(const bf16x8*)(&As[cur][wm + mi * 16 + r][(kk * 32 + kq * 8) ^ sx]);
#pragma unroll
      for (int ni = 0; ni < 2; ni++)
        bv[ni] = *(const bf16x8*)(&Bs[cur][wn + ni * 16 + r][(kk * 32 + kq * 8) ^ sx]);
#pragma unroll
      for (int mi = 0; mi < 2; mi++)
#pragma unroll
        for (int ni = 0; ni < 2; ni++)
          acc[mi][ni] = __builtin_amdgcn_mfma_f32_16x16x32_bf16(af[mi], bv[ni], acc[mi][ni], 0, 0, 0);
    }
    if (t <= 29) {
      int nb = cur - 1; if (nb < 0) nb += 3;   // buf (t+2) % 3
      STAGE(nb, (t + 2) * 64);
    }
    cur = (cur == 2) ? 0 : cur + 1;
  }

  const int rg = lane >> 4;
#pragma unroll
  for (int mi = 0; mi < 2; mi++)
#pragma unroll
    for (int ni = 0; ni < 2; ni++) {
      const int f = f0 + wn + ni * 16 + r;
#pragma unroll
      for (int rr = 0; rr < 4; rr++) {
        const int i = i0 + wm + mi * 16 + rg * 4 + rr;
        out[((size_t)b * NN + i) * FF + f] = leaky(acc[mi][ni][rr]);
      }
    }
}

extern "C" void kernel_launch(void* const* d_in, const int* in_sizes, int n_in,
                              void* d_out, int out_size, void* d_ws, size_t ws_size,
                              hipStream_t stream) {
  const float* h = (const float*)d_in[0];
  const float* W = (const float*)d_in[1];
  const float* a = (const float*)d_in[2];
  const int* adj = (const int*)d_in[3];
  float* out = (float*)d_out;

  char* ws = (char*)d_ws;
  u16* whT = (u16*)ws;                                    // 8 MiB [b][f][i]
  float* lpart = (float*)ws;                              // 8 MiB, ALIASES whT (consumed
                                                          // by k_lred before k_wh writes)
  u16* P = (u16*)(ws + (size_t)8388608);                  // 33.5 MiB [b][i][j]
  float* s1 = (float*)(ws + (size_t)8388608 + 33554432);  // 32 KiB
  float* s2 = s1 + BB * NN;                               // 32 KiB
  float* lsum = s2 + BB * NN;                             // 32 KiB
  float* wa1 = lsum + BB * NN;                            // 2 KiB
  float* wa2 = wa1 + FF;                                  // 2 KiB
  u16* hbf = (u16*)(wa2 + FF);                            // 8 MiB [row][f]
  u16* wt = hbf + (size_t)BB * NN * FF;                   // 512 KiB [f][k]

  k_wawt<<<dim3(192), 256, 0, stream>>>(W, a, wa1, wa2, wt);
  k_s<<<dim3(2048), 256, 0, stream>>>(h, wa1, wa2, s1, s2, hbf);
  k_l<<<dim3(256, 4), 512, 0, stream>>>(adj, s1, s2, lpart, P);
  k_lred<<<dim3(256), 256, 0, stream>>>(lpart, lsum);
  k_wh<<<dim3(1024), 256, 0, stream>>>(hbf, wt, lsum, whT);
  k_out<<<dim3(512), 512, 0, stream>>>(P, whT, out);
}